// Round 2
// baseline (230.664 us; speedup 1.0000x reference)
//
#include <hip/hip_runtime.h>

#define E_TOT 500000
#define BM 128
#define NBLK ((E_TOT + BM - 1) / BM)

typedef __attribute__((ext_vector_type(8))) short short8;
typedef __attribute__((ext_vector_type(4))) float f32x4;

__device__ __forceinline__ unsigned short f2bf(float f) {
  union { float f; unsigned u; } x; x.f = f;
  unsigned r = x.u + 0x7fffu + ((x.u >> 16) & 1u);
  return (unsigned short)(r >> 16);
}

__device__ __forceinline__ void gl_lds16(const void* g, void* l) {
  __builtin_amdgcn_global_load_lds(
      (const __attribute__((address_space(1))) void*)g,
      (__attribute__((address_space(3))) void*)l, 16, 0, 0);
}

// w1 (f32 [256][512]) -> w1r (bf16, layout [kb=0..63][n=0..255][j=0..7])
__global__ void k_repack_w1(const float* __restrict__ w1,
                            unsigned short* __restrict__ w1r) {
  int o = blockIdx.x * 256 + threadIdx.x;  // 131072 total
  int kb = o >> 11;
  int n = (o >> 3) & 255;
  int j = o & 7;
  w1r[o] = f2bf(w1[n * 512 + kb * 8 + j]);
}

__global__ __launch_bounds__(512, 4) void k_decoder(
    const float* __restrict__ zsrc, const float* __restrict__ zdst,
    const int* __restrict__ eli, const unsigned short* __restrict__ w1r,
    const float* __restrict__ b1, const float* __restrict__ w2,
    const float* __restrict__ b2, float* __restrict__ out) {
  // A: [kblk][edge][8] bf16 (16 KB)   B: [kblk][n][8] bf16 (32 KB)
  __shared__ unsigned short A_lds[8][BM][8];
  __shared__ unsigned short B_lds[8][256][8];
  __shared__ float partial[8][BM];  // 4 KB

  const unsigned tid = threadIdx.x;
  const unsigned l = tid & 63u;
  const unsigned w = tid >> 6;    // wave 0..7
  const unsigned l15 = l & 15u;
  const unsigned lg = l >> 4;     // 0..3

  const long e0 = (long)blockIdx.x * BM;

  // --- staging: lane stages edges eloc and eloc+64, k-slice koff..koff+7 ---
  const unsigned eloc = (w & 3u) * 16u + l15;       // 0..63
  const unsigned koff = (w >> 2) * 32u + lg * 8u;   // {0,8,...,56}

  const float* srcRow[2];
  const float* dstRow[2];
#pragma unroll
  for (int p = 0; p < 2; ++p) {
    long e = e0 + eloc + (long)p * 64;
    long eS = (e < E_TOT) ? e : (long)(E_TOT - 1);
    srcRow[p] = zsrc + (long)eli[eS] * 256;
    dstRow[p] = zdst + (long)eli[E_TOT + eS] * 256;
  }

  f32x4 acc[8][2];
#pragma unroll
  for (int mf = 0; mf < 8; ++mf)
#pragma unroll
    for (int nf = 0; nf < 2; ++nf)
      acc[mf][nf] = (f32x4){0.f, 0.f, 0.f, 0.f};

  // prologue: prefetch A for chunk 0 (src half, k base 0)
  f32x4 fa[2][2];
#pragma unroll
  for (int p = 0; p < 2; ++p) {
    fa[p][0] = ((const f32x4*)(srcRow[p] + koff))[0];
    fa[p][1] = ((const f32x4*)(srcRow[p] + koff))[1];
  }

  for (int c = 0; c < 8; ++c) {
    __syncthreads();  // previous compute done -> LDS writable

    // A(c): cvt regs -> bf16, one ds_write_b128 per lane per edge
#pragma unroll
    for (int p = 0; p < 2; ++p) {
      short8 sa;
      sa[0] = (short)f2bf(fa[p][0].x); sa[1] = (short)f2bf(fa[p][0].y);
      sa[2] = (short)f2bf(fa[p][0].z); sa[3] = (short)f2bf(fa[p][0].w);
      sa[4] = (short)f2bf(fa[p][1].x); sa[5] = (short)f2bf(fa[p][1].y);
      sa[6] = (short)f2bf(fa[p][1].z); sa[7] = (short)f2bf(fa[p][1].w);
      *(short8*)&A_lds[koff >> 3][eloc + p * 64u][0] = sa;
    }

    // B(c): 32 KB linear, 4 x global_load_lds(16B) per wave
    const unsigned short* bsrc = w1r + (unsigned)c * 16384u;
    unsigned short* bdst = (unsigned short*)B_lds;
#pragma unroll
    for (int q = 0; q < 4; ++q) {
      unsigned off = (w * 4u + (unsigned)q) * 512u;
      gl_lds16(bsrc + off + l * 8u, bdst + off);
    }

    __syncthreads();  // staging visible

    // prefetch A(c+1): latency hides under compute(c)
    if (c < 7) {
      int cn = c + 1;
#pragma unroll
      for (int p = 0; p < 2; ++p) {
        const float* half = (cn < 4) ? srcRow[p] : dstRow[p];
        const float* g = half + (unsigned)(cn & 3) * 64u + koff;
        fa[p][0] = ((const f32x4*)g)[0];
        fa[p][1] = ((const f32x4*)g)[1];
      }
    }

    // compute chunk c: 2 k-steps x (8 mf x 2 nf) MFMAs
#pragma unroll
    for (int ks = 0; ks < 2; ++ks) {
      short8 bfr0 = *(const short8*)&B_lds[ks * 4 + lg][w * 32u + l15][0];
      short8 bfr1 = *(const short8*)&B_lds[ks * 4 + lg][w * 32u + 16u + l15][0];
#pragma unroll
      for (int mf = 0; mf < 8; ++mf) {
        short8 afr = *(const short8*)&A_lds[ks * 4 + lg][mf * 16 + l15][0];
        acc[mf][0] =
            __builtin_amdgcn_mfma_f32_16x16x32_bf16(afr, bfr0, acc[mf][0], 0, 0, 0);
        acc[mf][1] =
            __builtin_amdgcn_mfma_f32_16x16x32_bf16(afr, bfr1, acc[mf][1], 0, 0, 0);
      }
    }
  }

  // ---- epilogue: h = relu(acc + b1); p = h . w2 ; reduce; sigmoid ----
  float b1v[2], w2v[2];
#pragma unroll
  for (int nf = 0; nf < 2; ++nf) {
    unsigned n = w * 32u + (unsigned)nf * 16u + l15;
    b1v[nf] = b1[n];
    w2v[nf] = w2[n];
  }
#pragma unroll
  for (int mf = 0; mf < 8; ++mf) {
#pragma unroll
    for (int r = 0; r < 4; ++r) {
      float p = 0.f;
#pragma unroll
      for (int nf = 0; nf < 2; ++nf) {
        float h = acc[mf][nf][r] + b1v[nf];
        h = fmaxf(h, 0.f);
        p = fmaf(h, w2v[nf], p);
      }
      // reduce across the 16 lanes (columns) of this fragment row
      p += __shfl_xor(p, 1);
      p += __shfl_xor(p, 2);
      p += __shfl_xor(p, 4);
      p += __shfl_xor(p, 8);
      if (l15 == 0) partial[w][mf * 16 + (int)lg * 4 + r] = p;
    }
  }
  __syncthreads();
  if (tid < BM) {
    long eo = e0 + (long)tid;
    if (eo < E_TOT) {
      float s = b2[0];
#pragma unroll
      for (int ww = 0; ww < 8; ++ww) s += partial[ww][tid];
      out[eo] = 1.f / (1.f + __expf(-s));
    }
  }
}

extern "C" void kernel_launch(void* const* d_in, const int* in_sizes, int n_in,
                              void* d_out, int out_size, void* d_ws,
                              size_t ws_size, hipStream_t stream) {
  const float* zsrc = (const float*)d_in[0];
  const float* zdst = (const float*)d_in[1];
  const int* eli = (const int*)d_in[2];
  const float* w1 = (const float*)d_in[3];
  const float* b1 = (const float*)d_in[4];
  const float* w2 = (const float*)d_in[5];
  const float* b2 = (const float*)d_in[6];
  float* out = (float*)d_out;
  unsigned short* w1r = (unsigned short*)d_ws;  // 256 KB

  k_repack_w1<<<512, 256, 0, stream>>>(w1, w1r);
  k_decoder<<<NBLK, 512, 0, stream>>>(zsrc, zdst, eli, w1r, b1, w2, b2, out);
}

// Round 3
// 176.693 us; speedup vs baseline: 1.3054x; 1.3054x over previous
//
#include <hip/hip_runtime.h>

#define E_TOT 500000
#define N_NODES 100000
#define BM 128
#define NBLK ((E_TOT + BM - 1) / BM)
#define NBH ((N_NODES + 63) / 64)   // 1563 row-blocks per half

typedef __attribute__((ext_vector_type(8))) short short8;
typedef __attribute__((ext_vector_type(4))) float f32x4;

__device__ __forceinline__ unsigned short f2bf(float f) {
  union { float f; unsigned u; } x; x.f = f;
  unsigned r = x.u + 0x7fffu + ((x.u >> 16) & 1u);
  return (unsigned short)(r >> 16);
}

__device__ __forceinline__ float bf2f(unsigned short s) {
  union { unsigned u; float f; } x; x.u = ((unsigned)s) << 16;
  return x.f;
}

__device__ __forceinline__ void gl_lds16(const void* g, void* l) {
  __builtin_amdgcn_global_load_lds(
      (const __attribute__((address_space(1))) void*)g,
      (__attribute__((address_space(3))) void*)l, 16, 0, 0);
}

// ===================== fast path: node-major =====================

// w1 (f32 [256][512]) -> w1r2 bf16 [half][kb=0..31][n=0..255][j=0..7]
// actual k = half*256 + kb*8 + j
__global__ void k_repack_w1h(const float* __restrict__ w1,
                             unsigned short* __restrict__ w1r2) {
  int o = blockIdx.x * 256 + threadIdx.x;  // 131072 total
  int half = o >> 16;
  int kb = (o >> 11) & 31;
  int n = (o >> 3) & 255;
  int j = o & 7;
  w1r2[o] = f2bf(w1[n * 512 + half * 256 + kb * 8 + j]);
}

// U'[n] = zsrc[n] @ W1s^T + b1  (half 0) ;  V[n] = zdst[n] @ W1d^T  (half 1)
// 64 rows/block, N=256, K=256 in 4 chunks of 64.
__global__ __launch_bounds__(512, 4) void k_node_gemm(
    const float* __restrict__ zsrc, const float* __restrict__ zdst,
    const unsigned short* __restrict__ w1r2, const float* __restrict__ b1,
    unsigned short* __restrict__ Uo, unsigned short* __restrict__ Vo) {
  __shared__ unsigned short A_lds[8][64][8];   // 8 KB
  __shared__ unsigned short B_lds[8][256][8];  // 32 KB

  const int bi = blockIdx.x;
  const int half = (bi >= NBH) ? 1 : 0;
  const int n0 = (bi - half * NBH) * 64;
  const float* Z = half ? zdst : zsrc;
  unsigned short* O = half ? Vo : Uo;

  const unsigned tid = threadIdx.x;
  const unsigned l = tid & 63u;
  const unsigned w = tid >> 6;
  const unsigned l15 = l & 15u;
  const unsigned lg = l >> 4;

  const unsigned rloc = (w & 3u) * 16u + l15;      // 0..63
  const unsigned koff = (w >> 2) * 32u + lg * 8u;  // 0..56

  int rS = n0 + (int)rloc;
  if (rS > N_NODES - 1) rS = N_NODES - 1;
  const float* arow = Z + (long)rS * 256;

  f32x4 acc[4][2];
#pragma unroll
  for (int mf = 0; mf < 4; ++mf)
#pragma unroll
    for (int nf = 0; nf < 2; ++nf) acc[mf][nf] = (f32x4){0.f, 0.f, 0.f, 0.f};

  f32x4 fa0 = ((const f32x4*)(arow + koff))[0];
  f32x4 fa1 = ((const f32x4*)(arow + koff))[1];

  for (int c = 0; c < 4; ++c) {
    __syncthreads();

    short8 sa;
    sa[0] = (short)f2bf(fa0.x); sa[1] = (short)f2bf(fa0.y);
    sa[2] = (short)f2bf(fa0.z); sa[3] = (short)f2bf(fa0.w);
    sa[4] = (short)f2bf(fa1.x); sa[5] = (short)f2bf(fa1.y);
    sa[6] = (short)f2bf(fa1.z); sa[7] = (short)f2bf(fa1.w);
    *(short8*)&A_lds[koff >> 3][rloc][0] = sa;

    const unsigned short* bsrc = w1r2 + half * 65536 + c * 16384;
    unsigned short* bdst = (unsigned short*)B_lds;
#pragma unroll
    for (int q = 0; q < 4; ++q) {
      unsigned off = (w * 4u + (unsigned)q) * 512u;
      gl_lds16(bsrc + off + l * 8u, bdst + off);
    }

    __syncthreads();

    if (c < 3) {
      const float* g = arow + (c + 1) * 64 + koff;
      fa0 = ((const f32x4*)g)[0];
      fa1 = ((const f32x4*)g)[1];
    }

#pragma unroll
    for (int ks = 0; ks < 2; ++ks) {
      short8 bfr0 = *(const short8*)&B_lds[ks * 4 + lg][w * 32u + l15][0];
      short8 bfr1 = *(const short8*)&B_lds[ks * 4 + lg][w * 32u + 16u + l15][0];
#pragma unroll
      for (int mf = 0; mf < 4; ++mf) {
        short8 afr = *(const short8*)&A_lds[ks * 4 + lg][mf * 16 + l15][0];
        acc[mf][0] =
            __builtin_amdgcn_mfma_f32_16x16x32_bf16(afr, bfr0, acc[mf][0], 0, 0, 0);
        acc[mf][1] =
            __builtin_amdgcn_mfma_f32_16x16x32_bf16(afr, bfr1, acc[mf][1], 0, 0, 0);
      }
    }
  }

  // epilogue: add b1 (half 0 only), cast bf16, store row-major
  float b1v[2];
#pragma unroll
  for (int nf = 0; nf < 2; ++nf)
    b1v[nf] = half ? 0.f : b1[w * 32u + nf * 16u + l15];
#pragma unroll
  for (int mf = 0; mf < 4; ++mf) {
#pragma unroll
    for (int nf = 0; nf < 2; ++nf) {
#pragma unroll
      for (int r = 0; r < 4; ++r) {
        int row = n0 + mf * 16 + (int)lg * 4 + r;
        if (row < N_NODES) {
          unsigned nn = w * 32u + (unsigned)nf * 16u + l15;
          O[(long)row * 256 + nn] = f2bf(acc[mf][nf][r] + b1v[nf]);
        }
      }
    }
  }
}

// per edge: out = sigmoid( w2 . relu(U'[row] + V[col]) + b2 )
#define EK_ITER 8
__global__ __launch_bounds__(256, 8) void k_edge(
    const unsigned short* __restrict__ U, const unsigned short* __restrict__ V,
    const int* __restrict__ eli, const float* __restrict__ w2,
    const float* __restrict__ b2, float* __restrict__ out) {
  const int tid = threadIdx.x;
  const int g = tid >> 4;  // group 0..15, one edge per group
  const int j = tid & 15;  // lane-in-group: dims 8j..8j+8 and 128+8j..
  float w2v[16];
#pragma unroll
  for (int q = 0; q < 8; ++q) {
    w2v[q] = w2[8 * j + q];
    w2v[8 + q] = w2[128 + 8 * j + q];
  }
  const float b2v = b2[0];
  const long base = (long)blockIdx.x * (16 * EK_ITER);
  for (int it = 0; it < EK_ITER; ++it) {
    long e = base + it * 16 + g;
    if (e >= E_TOT) break;
    int r = eli[e];
    int c = eli[E_TOT + e];
    const unsigned short* Ur = U + (long)r * 256;
    const unsigned short* Vr = V + (long)c * 256;
    short8 u0 = *(const short8*)(Ur + 8 * j);
    short8 u1 = *(const short8*)(Ur + 128 + 8 * j);
    short8 v0 = *(const short8*)(Vr + 8 * j);
    short8 v1 = *(const short8*)(Vr + 128 + 8 * j);
    float p = 0.f;
#pragma unroll
    for (int q = 0; q < 8; ++q) {
      float a0 = bf2f((unsigned short)u0[q]) + bf2f((unsigned short)v0[q]);
      float a1 = bf2f((unsigned short)u1[q]) + bf2f((unsigned short)v1[q]);
      a0 = fmaxf(a0, 0.f);
      a1 = fmaxf(a1, 0.f);
      p = fmaf(a0, w2v[q], p);
      p = fmaf(a1, w2v[8 + q], p);
    }
    p += __shfl_xor(p, 1);
    p += __shfl_xor(p, 2);
    p += __shfl_xor(p, 4);
    p += __shfl_xor(p, 8);
    if (j == 0) out[e] = 1.f / (1.f + __expf(-(p + b2v)));
  }
}

// ===================== fallback path (round-2 kernel) =====================

__global__ void k_repack_w1(const float* __restrict__ w1,
                            unsigned short* __restrict__ w1r) {
  int o = blockIdx.x * 256 + threadIdx.x;
  int kb = o >> 11;
  int n = (o >> 3) & 255;
  int j = o & 7;
  w1r[o] = f2bf(w1[n * 512 + kb * 8 + j]);
}

__global__ __launch_bounds__(512, 4) void k_decoder(
    const float* __restrict__ zsrc, const float* __restrict__ zdst,
    const int* __restrict__ eli, const unsigned short* __restrict__ w1r,
    const float* __restrict__ b1, const float* __restrict__ w2,
    const float* __restrict__ b2, float* __restrict__ out) {
  __shared__ unsigned short A_lds[8][BM][8];
  __shared__ unsigned short B_lds[8][256][8];
  __shared__ float partial[8][BM];

  const unsigned tid = threadIdx.x;
  const unsigned l = tid & 63u;
  const unsigned w = tid >> 6;
  const unsigned l15 = l & 15u;
  const unsigned lg = l >> 4;

  const long e0 = (long)blockIdx.x * BM;
  const unsigned eloc = (w & 3u) * 16u + l15;
  const unsigned koff = (w >> 2) * 32u + lg * 8u;

  const float* srcRow[2];
  const float* dstRow[2];
#pragma unroll
  for (int p = 0; p < 2; ++p) {
    long e = e0 + eloc + (long)p * 64;
    long eS = (e < E_TOT) ? e : (long)(E_TOT - 1);
    srcRow[p] = zsrc + (long)eli[eS] * 256;
    dstRow[p] = zdst + (long)eli[E_TOT + eS] * 256;
  }

  f32x4 acc[8][2];
#pragma unroll
  for (int mf = 0; mf < 8; ++mf)
#pragma unroll
    for (int nf = 0; nf < 2; ++nf) acc[mf][nf] = (f32x4){0.f, 0.f, 0.f, 0.f};

  f32x4 fa[2][2];
#pragma unroll
  for (int p = 0; p < 2; ++p) {
    fa[p][0] = ((const f32x4*)(srcRow[p] + koff))[0];
    fa[p][1] = ((const f32x4*)(srcRow[p] + koff))[1];
  }

  for (int c = 0; c < 8; ++c) {
    __syncthreads();
#pragma unroll
    for (int p = 0; p < 2; ++p) {
      short8 sa;
      sa[0] = (short)f2bf(fa[p][0].x); sa[1] = (short)f2bf(fa[p][0].y);
      sa[2] = (short)f2bf(fa[p][0].z); sa[3] = (short)f2bf(fa[p][0].w);
      sa[4] = (short)f2bf(fa[p][1].x); sa[5] = (short)f2bf(fa[p][1].y);
      sa[6] = (short)f2bf(fa[p][1].z); sa[7] = (short)f2bf(fa[p][1].w);
      *(short8*)&A_lds[koff >> 3][eloc + p * 64u][0] = sa;
    }
    const unsigned short* bsrc = w1r + (unsigned)c * 16384u;
    unsigned short* bdst = (unsigned short*)B_lds;
#pragma unroll
    for (int q = 0; q < 4; ++q) {
      unsigned off = (w * 4u + (unsigned)q) * 512u;
      gl_lds16(bsrc + off + l * 8u, bdst + off);
    }
    __syncthreads();
    if (c < 7) {
      int cn = c + 1;
#pragma unroll
      for (int p = 0; p < 2; ++p) {
        const float* half = (cn < 4) ? srcRow[p] : dstRow[p];
        const float* g = half + (unsigned)(cn & 3) * 64u + koff;
        fa[p][0] = ((const f32x4*)g)[0];
        fa[p][1] = ((const f32x4*)g)[1];
      }
    }
#pragma unroll
    for (int ks = 0; ks < 2; ++ks) {
      short8 bfr0 = *(const short8*)&B_lds[ks * 4 + lg][w * 32u + l15][0];
      short8 bfr1 = *(const short8*)&B_lds[ks * 4 + lg][w * 32u + 16u + l15][0];
#pragma unroll
      for (int mf = 0; mf < 8; ++mf) {
        short8 afr = *(const short8*)&A_lds[ks * 4 + lg][mf * 16 + l15][0];
        acc[mf][0] =
            __builtin_amdgcn_mfma_f32_16x16x32_bf16(afr, bfr0, acc[mf][0], 0, 0, 0);
        acc[mf][1] =
            __builtin_amdgcn_mfma_f32_16x16x32_bf16(afr, bfr1, acc[mf][1], 0, 0, 0);
      }
    }
  }

  float b1v[2], w2v[2];
#pragma unroll
  for (int nf = 0; nf < 2; ++nf) {
    unsigned n = w * 32u + (unsigned)nf * 16u + l15;
    b1v[nf] = b1[n];
    w2v[nf] = w2[n];
  }
#pragma unroll
  for (int mf = 0; mf < 8; ++mf) {
#pragma unroll
    for (int r = 0; r < 4; ++r) {
      float p = 0.f;
#pragma unroll
      for (int nf = 0; nf < 2; ++nf) {
        float h = acc[mf][nf][r] + b1v[nf];
        h = fmaxf(h, 0.f);
        p = fmaf(h, w2v[nf], p);
      }
      p += __shfl_xor(p, 1);
      p += __shfl_xor(p, 2);
      p += __shfl_xor(p, 4);
      p += __shfl_xor(p, 8);
      if (l15 == 0) partial[w][mf * 16 + (int)lg * 4 + r] = p;
    }
  }
  __syncthreads();
  if (tid < BM) {
    long eo = e0 + (long)tid;
    if (eo < E_TOT) {
      float s = b2[0];
#pragma unroll
      for (int ww = 0; ww < 8; ++ww) s += partial[ww][tid];
      out[eo] = 1.f / (1.f + __expf(-s));
    }
  }
}

// ===================== launch =====================

extern "C" void kernel_launch(void* const* d_in, const int* in_sizes, int n_in,
                              void* d_out, int out_size, void* d_ws,
                              size_t ws_size, hipStream_t stream) {
  const float* zsrc = (const float*)d_in[0];
  const float* zdst = (const float*)d_in[1];
  const int* eli = (const int*)d_in[2];
  const float* w1 = (const float*)d_in[3];
  const float* b1 = (const float*)d_in[4];
  const float* w2 = (const float*)d_in[5];
  const float* b2 = (const float*)d_in[6];
  float* out = (float*)d_out;

  const size_t uv_bytes = (size_t)N_NODES * 256 * 2;  // 51.2 MB each
  const size_t need = 2 * uv_bytes + 262144;

  if (ws_size >= need) {
    unsigned short* U = (unsigned short*)d_ws;
    unsigned short* V = (unsigned short*)((char*)d_ws + uv_bytes);
    unsigned short* w1r2 = (unsigned short*)((char*)d_ws + 2 * uv_bytes);
    k_repack_w1h<<<512, 256, 0, stream>>>(w1, w1r2);
    k_node_gemm<<<2 * NBH, 512, 0, stream>>>(zsrc, zdst, w1r2, b1, U, V);
    int nbe = (E_TOT + 16 * EK_ITER - 1) / (16 * EK_ITER);
    k_edge<<<nbe, 256, 0, stream>>>(U, V, eli, w2, b2, out);
  } else {
    unsigned short* w1r = (unsigned short*)d_ws;
    k_repack_w1<<<512, 256, 0, stream>>>(w1, w1r);
    k_decoder<<<NBLK, 512, 0, stream>>>(zsrc, zdst, eli, w1r, b1, w2, b2, out);
  }
}

// Round 4
// 152.282 us; speedup vs baseline: 1.5147x; 1.1603x over previous
//
#include <hip/hip_runtime.h>

#define E_TOT 500000
#define N_NODES 100000
#define RB 128
#define NBH2 ((N_NODES + RB - 1) / RB)  // 782
#define CSTR 264                        // C_lds row stride in shorts (528B, 16B-aligned)

typedef __attribute__((ext_vector_type(8))) short short8;
typedef __attribute__((ext_vector_type(4))) float f32x4;

__device__ __forceinline__ unsigned short f2bf(float f) {
  union { float f; unsigned u; } x; x.f = f;
  unsigned r = x.u + 0x7fffu + ((x.u >> 16) & 1u);
  return (unsigned short)(r >> 16);
}

__device__ __forceinline__ float bf2f(unsigned short s) {
  union { unsigned u; float f; } x; x.u = ((unsigned)s) << 16;
  return x.f;
}

__device__ __forceinline__ void gl_lds16(const void* g, void* l) {
  __builtin_amdgcn_global_load_lds(
      (const __attribute__((address_space(1))) void*)g,
      (__attribute__((address_space(3))) void*)l, 16, 0, 0);
}

// w1 (f32 [256][512]) -> w1r2 bf16 [half][kb=0..31][n=0..255][j=0..7]
__global__ void k_repack_w1h(const float* __restrict__ w1,
                             unsigned short* __restrict__ w1r2) {
  int o = blockIdx.x * 256 + threadIdx.x;  // 131072 total
  int half = o >> 16;
  int kb = (o >> 11) & 31;
  int n = (o >> 3) & 255;
  int j = o & 7;
  w1r2[o] = f2bf(w1[n * 512 + half * 256 + kb * 8 + j]);
}

// U'[n] = zsrc[n] @ W1s^T + b1 (half 0) ; V[n] = zdst[n] @ W1d^T (half 1)
// 128 rows/block, N=256, K=256 in 4 chunks of 64. Coalesced A loads.
__global__ __launch_bounds__(512, 4) void k_node_gemm(
    const float* __restrict__ zsrc, const float* __restrict__ zdst,
    const unsigned short* __restrict__ w1r2, const float* __restrict__ b1,
    unsigned short* __restrict__ Uo, unsigned short* __restrict__ Vo) {
  __shared__ __align__(16) char smem[RB * CSTR * 2];  // 67584 B
  unsigned short* A_lds = (unsigned short*)smem;            // [8][128][8] 16 KB
  unsigned short* B_lds = (unsigned short*)(smem + 16384);  // [8][256][8] 32 KB
  unsigned short* C_lds = (unsigned short*)smem;            // [128][CSTR] overlay

  const int bi = blockIdx.x;
  const int half = (bi >= NBH2) ? 1 : 0;
  const int n0 = (bi - half * NBH2) * RB;
  const float* Z = half ? zdst : zsrc;
  unsigned short* O = half ? Vo : Uo;

  const unsigned tid = threadIdx.x;
  const unsigned l = tid & 63u;
  const unsigned w = tid >> 6;
  const unsigned l15 = l & 15u;
  const unsigned lg = l >> 4;

  // A staging: lane covers rows (tid>>3) and (tid>>3)+64, k-slot kbl=tid&7
  const unsigned arow = tid >> 3;  // 0..63
  const unsigned kbl = tid & 7u;

  const float* aptr0;
  const float* aptr1;
  {
    int r0 = n0 + (int)arow;
    int r1 = n0 + (int)arow + 64;
    if (r0 > N_NODES - 1) r0 = N_NODES - 1;
    if (r1 > N_NODES - 1) r1 = N_NODES - 1;
    aptr0 = Z + (long)r0 * 256 + kbl * 8;
    aptr1 = Z + (long)r1 * 256 + kbl * 8;
  }

  f32x4 acc[8][2];
#pragma unroll
  for (int mf = 0; mf < 8; ++mf)
#pragma unroll
    for (int nf = 0; nf < 2; ++nf) acc[mf][nf] = (f32x4){0.f, 0.f, 0.f, 0.f};

  // prologue: prefetch chunk 0 (8 consecutive lanes read 256B contiguous)
  f32x4 fa00 = ((const f32x4*)aptr0)[0];
  f32x4 fa01 = ((const f32x4*)aptr0)[1];
  f32x4 fa10 = ((const f32x4*)aptr1)[0];
  f32x4 fa11 = ((const f32x4*)aptr1)[1];

  for (int c = 0; c < 4; ++c) {
    __syncthreads();  // prev MFMA reads done -> LDS writable

    short8 sa;
    sa[0] = (short)f2bf(fa00.x); sa[1] = (short)f2bf(fa00.y);
    sa[2] = (short)f2bf(fa00.z); sa[3] = (short)f2bf(fa00.w);
    sa[4] = (short)f2bf(fa01.x); sa[5] = (short)f2bf(fa01.y);
    sa[6] = (short)f2bf(fa01.z); sa[7] = (short)f2bf(fa01.w);
    *(short8*)&A_lds[(kbl * 128u + arow) * 8u] = sa;
    sa[0] = (short)f2bf(fa10.x); sa[1] = (short)f2bf(fa10.y);
    sa[2] = (short)f2bf(fa10.z); sa[3] = (short)f2bf(fa10.w);
    sa[4] = (short)f2bf(fa11.x); sa[5] = (short)f2bf(fa11.y);
    sa[6] = (short)f2bf(fa11.z); sa[7] = (short)f2bf(fa11.w);
    *(short8*)&A_lds[(kbl * 128u + arow + 64u) * 8u] = sa;

    // B chunk: 32 KB linear from L2-hot w1r2
    const unsigned short* bsrc = w1r2 + half * 65536 + c * 16384;
#pragma unroll
    for (int q = 0; q < 4; ++q) {
      unsigned off = (w * 4u + (unsigned)q) * 512u;
      gl_lds16(bsrc + off + l * 8u, B_lds + off);
    }

    __syncthreads();  // staging visible

    if (c < 3) {  // prefetch next chunk under MFMA
      const float* g0 = aptr0 + (c + 1) * 64;
      const float* g1 = aptr1 + (c + 1) * 64;
      fa00 = ((const f32x4*)g0)[0];
      fa01 = ((const f32x4*)g0)[1];
      fa10 = ((const f32x4*)g1)[0];
      fa11 = ((const f32x4*)g1)[1];
    }

#pragma unroll
    for (int ks = 0; ks < 2; ++ks) {
      unsigned kb = (unsigned)ks * 4u + lg;
      short8 bfr0 = *(const short8*)&B_lds[(kb * 256u + w * 32u + l15) * 8u];
      short8 bfr1 = *(const short8*)&B_lds[(kb * 256u + w * 32u + 16u + l15) * 8u];
#pragma unroll
      for (int mf = 0; mf < 8; ++mf) {
        short8 afr = *(const short8*)&A_lds[(kb * 128u + mf * 16u + l15) * 8u];
        acc[mf][0] =
            __builtin_amdgcn_mfma_f32_16x16x32_bf16(afr, bfr0, acc[mf][0], 0, 0, 0);
        acc[mf][1] =
            __builtin_amdgcn_mfma_f32_16x16x32_bf16(afr, bfr1, acc[mf][1], 0, 0, 0);
      }
    }
  }

  // epilogue: bias, cast, LDS transpose, coalesced 16B stores
  float b1v[2];
#pragma unroll
  for (int nf = 0; nf < 2; ++nf)
    b1v[nf] = half ? 0.f : b1[w * 32u + nf * 16u + l15];

  __syncthreads();  // all MFMA LDS reads done -> safe to overlay C
#pragma unroll
  for (int mf = 0; mf < 8; ++mf) {
#pragma unroll
    for (int nf = 0; nf < 2; ++nf) {
#pragma unroll
      for (int r = 0; r < 4; ++r) {
        unsigned row = mf * 16u + lg * 4u + (unsigned)r;
        unsigned col = w * 32u + (unsigned)nf * 16u + l15;
        C_lds[row * CSTR + col] = f2bf(acc[mf][nf][r] + b1v[nf]);
      }
    }
  }
  __syncthreads();
#pragma unroll
  for (int k = 0; k < 8; ++k) {
    unsigned u = tid + (unsigned)k * 512u;
    unsigned row = u >> 5;
    unsigned cu = u & 31u;
    if (n0 + (int)row < N_NODES) {
      short8 vv = *(const short8*)&C_lds[row * CSTR + cu * 8u];
      *(short8*)(O + (long)(n0 + row) * 256 + cu * 8u) = vv;
    }
  }
}

// per edge: out = sigmoid( w2 . relu(U'[row] + V[col]) + b2 )
// 3-stage pipeline: idx(e+2) || rows(e+1) || compute(e)
#define EK_ITER 16
__global__ __launch_bounds__(256, 6) void k_edge(
    const unsigned short* __restrict__ U, const unsigned short* __restrict__ V,
    const int* __restrict__ eli, const float* __restrict__ w2,
    const float* __restrict__ b2, float* __restrict__ out) {
  const int tid = threadIdx.x;
  const int g = tid >> 4;
  const int j = tid & 15;
  float w2v[16];
#pragma unroll
  for (int q = 0; q < 8; ++q) {
    w2v[q] = w2[8 * j + q];
    w2v[8 + q] = w2[128 + 8 * j + q];
  }
  const float b2v = b2[0];
  const long base = (long)blockIdx.x * (16 * EK_ITER) + g;  // edge k: base+16k

#define CLAMP_E(k) \
  (((base + 16 * (k)) < E_TOT) ? (base + 16 * (k)) : (long)(E_TOT - 1))

  // stage-in: idx for e0,e1; rows for e0
  long eP = CLAMP_E(0);
  int rA = eli[eP], cA = eli[E_TOT + eP];
  long eQ = CLAMP_E(1);
  int rB = eli[eQ], cB = eli[E_TOT + eQ];
  short8 uA0 = *(const short8*)(U + (long)rA * 256 + 8 * j);
  short8 uA1 = *(const short8*)(U + (long)rA * 256 + 128 + 8 * j);
  short8 vA0 = *(const short8*)(V + (long)cA * 256 + 8 * j);
  short8 vA1 = *(const short8*)(V + (long)cA * 256 + 128 + 8 * j);
  short8 uB0, uB1, vB0, vB1;

#pragma unroll
  for (int it2 = 0; it2 < EK_ITER / 2; ++it2) {
    // ---- phase A: compute edge 2*it2 (buf A); load rows(2*it2+1); idx(2*it2+2)
    {
      long eN = CLAMP_E(2 * it2 + 2);
      int rN = eli[eN], cN = eli[E_TOT + eN];
      uB0 = *(const short8*)(U + (long)rB * 256 + 8 * j);
      uB1 = *(const short8*)(U + (long)rB * 256 + 128 + 8 * j);
      vB0 = *(const short8*)(V + (long)cB * 256 + 8 * j);
      vB1 = *(const short8*)(V + (long)cB * 256 + 128 + 8 * j);
      rB = rN; cB = cN;  // idx now one step ahead of rows
      float p = 0.f;
#pragma unroll
      for (int q = 0; q < 8; ++q) {
        float a0 = bf2f((unsigned short)uA0[q]) + bf2f((unsigned short)vA0[q]);
        float a1 = bf2f((unsigned short)uA1[q]) + bf2f((unsigned short)vA1[q]);
        p = fmaf(fmaxf(a0, 0.f), w2v[q], p);
        p = fmaf(fmaxf(a1, 0.f), w2v[8 + q], p);
      }
      p += __shfl_xor(p, 1);
      p += __shfl_xor(p, 2);
      p += __shfl_xor(p, 4);
      p += __shfl_xor(p, 8);
      long e = base + 16 * (2 * it2);
      if (j == 0 && e < E_TOT) out[e] = 1.f / (1.f + __expf(-(p + b2v)));
    }
    // ---- phase B: compute edge 2*it2+1 (buf B); load rows(2*it2+2); idx(2*it2+3)
    {
      long eN = CLAMP_E(2 * it2 + 3);
      int rN = eli[eN], cN = eli[E_TOT + eN];
      uA0 = *(const short8*)(U + (long)rB * 256 + 8 * j);
      uA1 = *(const short8*)(U + (long)rB * 256 + 128 + 8 * j);
      vA0 = *(const short8*)(V + (long)cB * 256 + 8 * j);
      vA1 = *(const short8*)(V + (long)cB * 256 + 128 + 8 * j);
      rB = rN; cB = cN;
      float p = 0.f;
#pragma unroll
      for (int q = 0; q < 8; ++q) {
        float a0 = bf2f((unsigned short)uB0[q]) + bf2f((unsigned short)vB0[q]);
        float a1 = bf2f((unsigned short)uB1[q]) + bf2f((unsigned short)vB1[q]);
        p = fmaf(fmaxf(a0, 0.f), w2v[q], p);
        p = fmaf(fmaxf(a1, 0.f), w2v[8 + q], p);
      }
      p += __shfl_xor(p, 1);
      p += __shfl_xor(p, 2);
      p += __shfl_xor(p, 4);
      p += __shfl_xor(p, 8);
      long e = base + 16 * (2 * it2 + 1);
      if (j == 0 && e < E_TOT) out[e] = 1.f / (1.f + __expf(-(p + b2v)));
    }
  }
#undef CLAMP_E
}

extern "C" void kernel_launch(void* const* d_in, const int* in_sizes, int n_in,
                              void* d_out, int out_size, void* d_ws,
                              size_t ws_size, hipStream_t stream) {
  const float* zsrc = (const float*)d_in[0];
  const float* zdst = (const float*)d_in[1];
  const int* eli = (const int*)d_in[2];
  const float* w1 = (const float*)d_in[3];
  const float* b1 = (const float*)d_in[4];
  const float* w2 = (const float*)d_in[5];
  const float* b2 = (const float*)d_in[6];
  float* out = (float*)d_out;

  const size_t uv_bytes = (size_t)N_NODES * 256 * 2;  // 51.2 MB each
  unsigned short* U = (unsigned short*)d_ws;
  unsigned short* V = (unsigned short*)((char*)d_ws + uv_bytes);
  unsigned short* w1r2 = (unsigned short*)((char*)d_ws + 2 * uv_bytes);

  k_repack_w1h<<<512, 256, 0, stream>>>(w1, w1r2);
  k_node_gemm<<<2 * NBH2, 512, 0, stream>>>(zsrc, zdst, w1r2, b1, U, V);
  int nbe = (E_TOT + 16 * EK_ITER - 1) / (16 * EK_ITER);
  k_edge<<<nbe, 256, 0, stream>>>(U, V, eli, w2, b2, out);
}